// Round 5
// baseline (174.406 us; speedup 1.0000x reference)
//
#include <hip/hip_runtime.h>

#define FRAME 160
#define ORDER 12
#define NFRAMES (4096 * 15)
#define EPL 10            // elements per sub-lane (16 lanes per frame-pair)

typedef float v2f __attribute__((ext_vector_type(2)));

__device__ __forceinline__ v2f pkfma(v2f a, v2f b, v2f c) {
    return __builtin_elementwise_fma(a, b, c);
}
__device__ __forceinline__ v2f splat2(float v) { v2f r; r.x = v; r.y = v; return r; }

template<int CTRL>
__device__ __forceinline__ float dppf(float v) {
    return __int_as_float(__builtin_amdgcn_update_dpp(
        0, __float_as_int(v), CTRL, 0xF, 0xF, true));
}

// Sum across each 16-lane row, pure-VALU DPP; bit-identical in all 16 lanes.
__device__ __forceinline__ float rowsum16(float v) {
    v += dppf<0xB1>(v);    // quad_perm [1,0,3,2]  : lane ^= 1
    v += dppf<0x4E>(v);    // quad_perm [2,3,0,1]  : lane ^= 2
    v += dppf<0x140>(v);   // row_mirror
    v += dppf<0x141>(v);   // row_half_mirror
    return v;
}
__device__ __forceinline__ v2f rowsum16v(v2f v) {  // two independent chains (ILP x2)
    v2f r; r.x = rowsum16(v.x); r.y = rowsum16(v.y); return r;
}

// No pcm LDS staging: each lane's Burg window (p0..p0+10) and FIR window
// (p0-12..p0+9) are contiguous, 8B-aligned global ranges -> direct float2
// loads (L1/L2-hot on the FIR re-read). LDS shrinks 13KB -> ~1.7KB, so the
// limiter becomes the 2048-thread/CU slot cap: 16 blocks x 2 waves = 32
// waves/CU (was ~24 LDS-capped).
//
// Zero-history semantics (lfilter zero init, per frame): position x[p] with
// p<0 contributes 0. Lane s touches p in [p0-12, p0+9]; negative p occurs
// for s==0 (12 zeros) AND s==1 (2 zeros). Guard is per float2-pair:
// p0-12+j >= 0  <=>  p0+j >= ORDER. (Round-3 bug: guarded only s==0 ->
// s==1 read pcm[-2] at frame 0 = OOB fault + prev-frame leakage elsewhere.)
__global__ __launch_bounds__(128, 8) void ResidualEmbedding_70798240907390_kernel(
    const int* __restrict__ bits, const float* __restrict__ pcm,
    const float* __restrict__ alpha_p, float* __restrict__ out)
{
    const int tid  = threadIdx.x;
    const int wave = tid >> 6;
    const int lane = tid & 63;
    const int g    = lane >> 4;          // frame-PAIR group within wave
    const int s    = lane & 15;
    const int wf0  = (blockIdx.x * 2 + wave) * 8;   // 8 frames per wave
    const int fA   = wf0 + 2 * g;
    const int fB   = fA + 1;

    __shared__ float s_win[161];
    __shared__ v2f  s_a[2][4][16];

    // Hann window: each wave writes ALL entries (identical values -> benign
    // race; own-wave writes are ordered before own-wave reads, no barrier).
    {
        const float kW = 6.2831853071795864769f / 159.0f;
        for (int j = lane; j < 161; j += 64) {
            s_win[j] = (j < 160) ? 0.5f - 0.5f * __cosf(kW * (float)j) : 0.0f;
        }
    }
    __builtin_amdgcn_wave_barrier();

    const int p0 = s * EPL;
    const float* pA = pcm + (size_t)fA * FRAME + p0;
    const float* pB = pcm + (size_t)fB * FRAME + p0;

    // Raw samples p0..p0+10, pair-packed. j=10 guarded: s==15 would read the
    // next frame (and 1-past-end at the very last frame).
    v2f pr[EPL + 1];
#pragma unroll
    for (int j = 0; j < EPL; j += 2) {
        float2 a2 = *(const float2*)(pA + j);
        float2 b2 = *(const float2*)(pB + j);
        pr[j].x     = a2.x; pr[j].y     = b2.x;
        pr[j + 1].x = a2.y; pr[j + 1].y = b2.y;
    }
    pr[EPL] = splat2(0.f);
    if (s < 15) { pr[EPL].x = pA[EPL]; pr[EPL].y = pB[EPL]; }

    // Window in place; b[p]=xw[p], f[p]=xw[p+1]; position 159 zero invariant
    // (pr[10] = 0 for s==15 AND win[160] = 0).
    v2f F[EPL], B[EPL];
#pragma unroll
    for (int j = 0; j <= EPL; ++j) pr[j] *= s_win[p0 + j];
#pragma unroll
    for (int t = 0; t < EPL; ++t) { F[t] = pr[t + 1]; B[t] = pr[t]; }
    if (s == 15) B[EPL - 1] = splat2(0.f);

    v2f dpF = splat2(0.f), dpB = splat2(0.f);
#pragma unroll
    for (int t = 0; t < EPL; ++t) {
        dpF = pkfma(F[t], F[t], dpF);
        dpB = pkfma(B[t], B[t], dpB);
    }
    v2f den = rowsum16v(dpF + dpB);

    v2f a  = (s == 0) ? splat2(1.f) : splat2(0.f);
    v2f ar = (s == 1) ? splat2(1.f) : splat2(0.f);
    v2f cp = splat2(0.f), dsc = splat2(0.f);

#pragma unroll
    for (int i = 0; i < ORDER; ++i) {
        v2f q0 = splat2(0.f), q1 = splat2(0.f);
#pragma unroll
        for (int t = 0; t < EPL; t += 2) {
            q0 = pkfma(F[t],     B[t],     q0);
            q1 = pkfma(F[t + 1], B[t + 1], q1);
        }
        v2f num = rowsum16v(q0 + q1);
        if (i > 0) den = dsc - rowsum16v(cp);
        v2f r;
        r.x = -2.0f * num.x * __builtin_amdgcn_rcpf(den.x);
        r.y = -2.0f * num.y * __builtin_amdgcn_rcpf(den.y);

        // a[:i+2] += r*a[:i+2][::-1]:  a'=a+r*ar ; ar'=(ar+r*a)>>1 lane
        v2f an  = pkfma(r, ar, a);
        v2f arn = pkfma(r, a, ar);
        a = an;
        ar.x = dppf<0x111>(arn.x);       // row_shr:1, lane0 <- 0
        ar.y = dppf<0x111>(arn.y);

        // In-place lattice update (each pk op serves BOTH frames).
#pragma unroll
        for (int t = 0; t < EPL; ++t) {
            v2f fo = F[t];
            F[t] = pkfma(r, B[t], fo);
            B[t] = pkfma(r, fo, B[t]);
        }

        const int pe = 158 - i;          // compile-time (full unroll)
        const int SL = pe / EPL, SS = pe % EPL;
        v2f fe = (s == 0)  ? F[0]  : splat2(0.f);
        v2f be = (s == SL) ? B[SS] : splat2(0.f);
        cp  = pkfma(fe, fe, be * be);
        dsc = pkfma(-(r * r), den, den); // (1-r^2)*den

        // f = f'[1:]  (row_shl:1; lane15 -> 0 keeps invariant)
        v2f up;
        up.x = dppf<0x101>(F[0].x);
        up.y = dppf<0x101>(F[0].y);
#pragma unroll
        for (int t = 0; t < EPL - 1; ++t) F[t] = F[t + 1];
        F[EPL - 1] = up;
        if (s == SL) B[SS] = splat2(0.f);
    }

    // Broadcast packed a[0..12] within the group via same-wave LDS bounce.
    s_a[wave][g][s] = a;
    __builtin_amdgcn_wave_barrier();
    v2f ak[ORDER + 1];
#pragma unroll
    for (int k = 0; k <= ORDER; ++k) ak[k] = s_a[wave][g][k];

    // FIR window re-read straight from global (L1/L2-hot). Xw[j] = x[p0-12+j].
    // Per-pair zero-history guard: load only when p0-12+j >= 0; both elements
    // of the pair are then in-frame (max index 149). Masked pairs = zeros,
    // exactly the old LDS front-pad semantics (covers s==0 fully, s==1 j=0).
    v2f Xw[EPL + ORDER];
#pragma unroll
    for (int j = 0; j < ORDER; j += 2) {
        Xw[j]     = splat2(0.f);
        Xw[j + 1] = splat2(0.f);
        if (p0 + j >= ORDER) {
            float2 a2 = *(const float2*)(pA - ORDER + j);
            float2 b2 = *(const float2*)(pB - ORDER + j);
            Xw[j].x     = a2.x; Xw[j].y     = b2.x;
            Xw[j + 1].x = a2.y; Xw[j + 1].y = b2.y;
        }
    }
#pragma unroll
    for (int j = 0; j < EPL; j += 2) {
        float2 a2 = *(const float2*)(pA + j);
        float2 b2 = *(const float2*)(pB + j);
        Xw[ORDER + j].x     = a2.x; Xw[ORDER + j].y     = b2.x;
        Xw[ORDER + j + 1].x = a2.y; Xw[ORDER + j + 1].y = b2.y;
    }

    const float alpha = alpha_p[0];
    v2f ac;
    ac.x = alpha * (2.0f * (float)bits[fA] - 1.0f);
    ac.y = alpha * (2.0f * (float)bits[fB] - 1.0f);

    float* oA = out + (size_t)fA * FRAME + p0;
    float* oB = out + (size_t)fB * FRAME + p0;
#pragma unroll
    for (int t = 0; t < EPL; t += 2) {
        v2f acc0 = splat2(0.f), acc1 = splat2(0.f);
#pragma unroll
        for (int k = 0; k <= ORDER; ++k) {
            acc0 = pkfma(ak[k], Xw[ORDER + t - k],     acc0);
            acc1 = pkfma(ak[k], Xw[ORDER + t + 1 - k], acc1);
        }
        v2f r0 = pkfma(ac, acc0, Xw[ORDER + t]);
        v2f r1 = pkfma(ac, acc1, Xw[ORDER + t + 1]);
        *(float2*)(oA + t) = make_float2(r0.x, r1.x);
        *(float2*)(oB + t) = make_float2(r0.y, r1.y);
    }
}

extern "C" void kernel_launch(void* const* d_in, const int* in_sizes, int n_in,
                              void* d_out, int out_size, void* d_ws, size_t ws_size,
                              hipStream_t stream) {
    const int*   bits  = (const int*)d_in[0];
    const float* pcm   = (const float*)d_in[1];
    const float* alpha = (const float*)d_in[2];
    float*       out   = (float*)d_out;

    // 61440 frames; 16 per block (2 waves x 4 groups x 2 packed frames).
    dim3 grid(NFRAMES / 16), block(128);
    hipLaunchKernelGGL(ResidualEmbedding_70798240907390_kernel, grid, block, 0, stream,
                       bits, pcm, alpha, out);
}

// Round 6
// 108.331 us; speedup vs baseline: 1.6099x; 1.6099x over previous
//
#include <hip/hip_runtime.h>

#define FRAME 160
#define ORDER 12
#define NFRAMES (4096 * 15)
#define EPL 10            // elements per sub-lane (16 lanes per frame-pair)
#define ROWP 174          // 12 front pad + 160 + 1 zero tail + 1 align pad (16B row stride)

typedef float v2f __attribute__((ext_vector_type(2)));

__device__ __forceinline__ v2f pkfma(v2f a, v2f b, v2f c) {
    return __builtin_elementwise_fma(a, b, c);
}
__device__ __forceinline__ v2f splat2(float v) { v2f r; r.x = v; r.y = v; return r; }

template<int CTRL>
__device__ __forceinline__ float dppf(float v) {
    return __int_as_float(__builtin_amdgcn_update_dpp(
        0, __float_as_int(v), CTRL, 0xF, 0xF, true));
}

// Sum across each 16-lane row, pure-VALU DPP; bit-identical in all 16 lanes.
__device__ __forceinline__ float rowsum16(float v) {
    v += dppf<0xB1>(v);    // quad_perm [1,0,3,2]  : lane ^= 1
    v += dppf<0x4E>(v);    // quad_perm [2,3,0,1]  : lane ^= 2
    v += dppf<0x140>(v);   // row_mirror
    v += dppf<0x141>(v);   // row_half_mirror
    return v;
}
__device__ __forceinline__ v2f rowsum16v(v2f v) {  // two independent chains (ILP x2)
    v2f r; r.x = rowsum16(v.x); r.y = rowsum16(v.y); return r;
}

// Round-3 structure (best measured): 2-wave blocks, float4-coalesced
// pcm->LDS staging, barrier-free (all LDS wave-local). NEW: the output path
// bounces FIR results through the dead s_x staging buffer so global stores
// are float4 at 256B/frame segments (round-2 counters showed the old 8B
// lane-strided float2 stores cost 1.9x WRITE amplification; round 4 showed
// the full-scatter version cost 5.5x).
// LDS ~13KB/block -> 12 blocks/CU -> 24 waves/CU; hence min-waves 6 (not 8):
// occupancy is LDS-capped, give regalloc the slack.
__global__ __launch_bounds__(128, 6) void ResidualEmbedding_70798240907390_kernel(
    const int* __restrict__ bits, const float* __restrict__ pcm,
    const float* __restrict__ alpha_p, float* __restrict__ out)
{
    const int tid  = threadIdx.x;
    const int wave = tid >> 6;
    const int lane = tid & 63;
    const int g    = lane >> 4;          // frame-PAIR group within wave
    const int s    = lane & 15;
    const int wf0  = (blockIdx.x * 2 + wave) * 8;   // 8 frames per wave
    const int fA   = wf0 + 2 * g;
    const int fB   = fA + 1;

    __shared__ __align__(16) v2f s_x[2][4][ROWP];
    __shared__ float s_win[161];
    __shared__ v2f  s_a[2][4][16];

    // Hann window: each wave writes ALL entries (identical values -> benign
    // race; own-wave writes are ordered before own-wave reads, no barrier).
    {
        const float kW = 6.2831853071795864769f / 159.0f;
        for (int j = lane; j < 161; j += 64) {
            s_win[j] = (j < 160) ? 0.5f - 0.5f * __cosf(kW * (float)j) : 0.0f;
        }
    }
    // Zero front pads (12 pairs x 4 rows) and tail pad (1 pair x 4 rows).
    if (lane < 48) { int gr = lane / 12, j = lane % 12; s_x[wave][gr][j] = splat2(0.f); }
    if (lane < 4)  s_x[wave][lane][172] = splat2(0.f);

    // Stage: coalesced float4 per frame, written pair-interleaved as 2x b128.
    {
        const float* pAg = pcm + (size_t)fA * FRAME;
        const float* pBg = pcm + (size_t)fB * FRAME;
#pragma unroll
        for (int c = 0; c < 3; ++c) {
            int p = 4 * s + 64 * c;
            if (p < FRAME) {
                float4 a4 = *(const float4*)(pAg + p);
                float4 b4 = *(const float4*)(pBg + p);
                float4* dst = (float4*)&s_x[wave][g][12 + p];   // 16B aligned
                dst[0] = make_float4(a4.x, b4.x, a4.y, b4.y);
                dst[1] = make_float4(a4.z, b4.z, a4.w, b4.w);
            }
        }
    }
    __builtin_amdgcn_wave_barrier();

    const v2f* X = &s_x[wave][g][12];    // X[p] = {xA[p], xB[p]}, p in [-12, 160]
    const int p0 = s * EPL;

    // Windowed products; b[p]=xw[p], f[p]=xw[p+1]; position 159 zero invariant
    // (X[160] = 0 via tail pad AND win[160] = 0).
    v2f F[EPL], B[EPL];
    {
        v2f pr[EPL + 1];
#pragma unroll
        for (int j = 0; j <= EPL; ++j)
            pr[j] = X[p0 + j] * s_win[p0 + j];
#pragma unroll
        for (int t = 0; t < EPL; ++t) { F[t] = pr[t + 1]; B[t] = pr[t]; }
    }
    if (s == 15) B[EPL - 1] = splat2(0.f);
    v2f dpF = splat2(0.f), dpB = splat2(0.f);
#pragma unroll
    for (int t = 0; t < EPL; ++t) {
        dpF = pkfma(F[t], F[t], dpF);
        dpB = pkfma(B[t], B[t], dpB);
    }
    v2f den = rowsum16v(dpF + dpB);

    v2f a  = (s == 0) ? splat2(1.f) : splat2(0.f);
    v2f ar = (s == 1) ? splat2(1.f) : splat2(0.f);
    v2f cp = splat2(0.f), dsc = splat2(0.f);

#pragma unroll
    for (int i = 0; i < ORDER; ++i) {
        v2f q0 = splat2(0.f), q1 = splat2(0.f);
#pragma unroll
        for (int t = 0; t < EPL; t += 2) {
            q0 = pkfma(F[t],     B[t],     q0);
            q1 = pkfma(F[t + 1], B[t + 1], q1);
        }
        v2f num = rowsum16v(q0 + q1);
        if (i > 0) den = dsc - rowsum16v(cp);
        v2f r;
        r.x = -2.0f * num.x * __builtin_amdgcn_rcpf(den.x);
        r.y = -2.0f * num.y * __builtin_amdgcn_rcpf(den.y);

        // a[:i+2] += r*a[:i+2][::-1]:  a'=a+r*ar ; ar'=(ar+r*a)>>1 lane
        v2f an  = pkfma(r, ar, a);
        v2f arn = pkfma(r, a, ar);
        a = an;
        ar.x = dppf<0x111>(arn.x);       // row_shr:1, lane0 <- 0
        ar.y = dppf<0x111>(arn.y);

        // In-place lattice update (each pk op serves BOTH frames).
#pragma unroll
        for (int t = 0; t < EPL; ++t) {
            v2f fo = F[t];
            F[t] = pkfma(r, B[t], fo);
            B[t] = pkfma(r, fo, B[t]);
        }

        const int pe = 158 - i;          // compile-time (full unroll)
        const int SL = pe / EPL, SS = pe % EPL;
        v2f fe = (s == 0)  ? F[0]  : splat2(0.f);
        v2f be = (s == SL) ? B[SS] : splat2(0.f);
        cp  = pkfma(fe, fe, be * be);
        dsc = pkfma(-(r * r), den, den); // (1-r^2)*den

        // f = f'[1:]  (row_shl:1; lane15 -> 0 keeps invariant)
        v2f up;
        up.x = dppf<0x101>(F[0].x);
        up.y = dppf<0x101>(F[0].y);
#pragma unroll
        for (int t = 0; t < EPL - 1; ++t) F[t] = F[t + 1];
        F[EPL - 1] = up;
        if (s == SL) B[SS] = splat2(0.f);
    }

    // Broadcast packed a[0..12] within the group via same-wave LDS bounce.
    s_a[wave][g][s] = a;
    __builtin_amdgcn_wave_barrier();
    v2f ak[ORDER + 1];
#pragma unroll
    for (int k = 0; k <= ORDER; ++k) ak[k] = s_a[wave][g][k];

    // FIR window straight from pair-interleaved LDS (front pad = zero
    // history). ALL Xw values land in registers before s_x is overwritten
    // below (in-order per-wave LDS pipe + compiler barrier).
    v2f Xw[EPL + ORDER];
#pragma unroll
    for (int j = 0; j < EPL + ORDER; ++j) Xw[j] = X[p0 - ORDER + j];
    __builtin_amdgcn_wave_barrier();

    const float alpha = alpha_p[0];
    v2f ac;
    ac.x = alpha * (2.0f * (float)bits[fA] - 1.0f);
    ac.y = alpha * (2.0f * (float)bits[fB] - 1.0f);

    // FIR; results written pair-interleaved back into s_x (b128, aligned:
    // p0 even). Inputs are all in registers -> overwrite is race-free.
    {
        v2f* W = (v2f*)&s_x[wave][g][12];
#pragma unroll
        for (int t = 0; t < EPL; t += 2) {
            v2f acc0 = splat2(0.f), acc1 = splat2(0.f);
#pragma unroll
            for (int k = 0; k <= ORDER; ++k) {
                acc0 = pkfma(ak[k], Xw[ORDER + t - k],     acc0);
                acc1 = pkfma(ak[k], Xw[ORDER + t + 1 - k], acc1);
            }
            v2f r0 = pkfma(ac, acc0, Xw[ORDER + t]);
            v2f r1 = pkfma(ac, acc1, Xw[ORDER + t + 1]);
            *(float4*)&W[p0 + t] = make_float4(r0.x, r0.y, r1.x, r1.y);
        }
    }
    __builtin_amdgcn_wave_barrier();

    // Coalesced output: float4 per frame, 256B contiguous per 16-lane group
    // (mirror of the load staging). Same wave wrote all 10 pair-slots above;
    // per-wave in-order LDS pipe makes the read-back safe.
    {
        float* oAf = out + (size_t)fA * FRAME;
        float* oBf = out + (size_t)fB * FRAME;
#pragma unroll
        for (int c = 0; c < 3; ++c) {
            int p = 4 * s + 64 * c;
            if (p < FRAME) {
                const float4* src = (const float4*)&s_x[wave][g][12 + p];
                float4 q0 = src[0], q1 = src[1];
                // q0={A[p],B[p],A[p+1],B[p+1]}, q1={A[p+2],B[p+2],A[p+3],B[p+3]}
                *(float4*)(oAf + p) = make_float4(q0.x, q0.z, q1.x, q1.z);
                *(float4*)(oBf + p) = make_float4(q0.y, q0.w, q1.y, q1.w);
            }
        }
    }
}

extern "C" void kernel_launch(void* const* d_in, const int* in_sizes, int n_in,
                              void* d_out, int out_size, void* d_ws, size_t ws_size,
                              hipStream_t stream) {
    const int*   bits  = (const int*)d_in[0];
    const float* pcm   = (const float*)d_in[1];
    const float* alpha = (const float*)d_in[2];
    float*       out   = (float*)d_out;

    // 61440 frames; 16 per block (2 waves x 4 groups x 2 packed frames).
    dim3 grid(NFRAMES / 16), block(128);
    hipLaunchKernelGGL(ResidualEmbedding_70798240907390_kernel, grid, block, 0, stream,
                       bits, pcm, alpha, out);
}

// Round 7
// 105.751 us; speedup vs baseline: 1.6492x; 1.0244x over previous
//
#include <hip/hip_runtime.h>

#define FRAME 160
#define ORDER 12
#define NFRAMES (4096 * 15)
#define EPL 10            // elements per sub-lane (16 lanes per frame-pair)
#define ROWP 174          // 12 front pad + 160 + 1 zero tail + 1 align pad (16B row stride)

typedef float v2f __attribute__((ext_vector_type(2)));

__device__ __forceinline__ v2f pkfma(v2f a, v2f b, v2f c) {
    return __builtin_elementwise_fma(a, b, c);
}
__device__ __forceinline__ v2f splat2(float v) { v2f r; r.x = v; r.y = v; return r; }

template<int CTRL>
__device__ __forceinline__ float dppf(float v) {
    return __int_as_float(__builtin_amdgcn_update_dpp(
        0, __float_as_int(v), CTRL, 0xF, 0xF, true));
}

// Sum across each 16-lane row, pure-VALU DPP; bit-identical in all 16 lanes.
__device__ __forceinline__ float rowsum16(float v) {
    v += dppf<0xB1>(v);    // quad_perm [1,0,3,2]  : lane ^= 1
    v += dppf<0x4E>(v);    // quad_perm [2,3,0,1]  : lane ^= 2
    v += dppf<0x140>(v);   // row_mirror
    v += dppf<0x141>(v);   // row_half_mirror
    return v;
}
__device__ __forceinline__ v2f rowsum16v(v2f v) {  // two independent chains (ILP x2)
    v2f r; r.x = rowsum16(v.x); r.y = rowsum16(v.y); return r;
}

// Round-3 structure (best measured, dur 104.26): 2-wave blocks, float4-
// coalesced pcm->LDS staging, barrier-free (all LDS wave-local), direct
// global stores. NEW vs round 3: the FIR phase is remapped so each lane
// produces 4 CONTIGUOUS positions per chunk (p = 4s + 64c, c=0..2), giving
// aligned float4 stores (256B contiguous per 16-lane group) straight from
// registers -- kills the 1.9x WRITE amplification round-2 counters showed
// for 8B/40B-stride float2 stores, WITHOUT round-5's LDS bounce (which
// measured -4us). Tap order (k ascending) identical -> bit-identical output.
__global__ __launch_bounds__(128, 6) void ResidualEmbedding_70798240907390_kernel(
    const int* __restrict__ bits, const float* __restrict__ pcm,
    const float* __restrict__ alpha_p, float* __restrict__ out)
{
    const int tid  = threadIdx.x;
    const int wave = tid >> 6;
    const int lane = tid & 63;
    const int g    = lane >> 4;          // frame-PAIR group within wave
    const int s    = lane & 15;
    const int wf0  = (blockIdx.x * 2 + wave) * 8;   // 8 frames per wave
    const int fA   = wf0 + 2 * g;
    const int fB   = fA + 1;

    __shared__ __align__(16) v2f s_x[2][4][ROWP];
    __shared__ float s_win[161];
    __shared__ v2f  s_a[2][4][16];

    // Hann window: each wave writes ALL entries (identical values -> benign
    // race; own-wave writes are ordered before own-wave reads, no barrier).
    {
        const float kW = 6.2831853071795864769f / 159.0f;
        for (int j = lane; j < 161; j += 64) {
            s_win[j] = (j < 160) ? 0.5f - 0.5f * __cosf(kW * (float)j) : 0.0f;
        }
    }
    // Zero front pads (12 pairs x 4 rows) and tail pad (1 pair x 4 rows).
    if (lane < 48) { int gr = lane / 12, j = lane % 12; s_x[wave][gr][j] = splat2(0.f); }
    if (lane < 4)  s_x[wave][lane][172] = splat2(0.f);

    // Stage: coalesced float4 per frame, written pair-interleaved as 2x b128.
    {
        const float* pAg = pcm + (size_t)fA * FRAME;
        const float* pBg = pcm + (size_t)fB * FRAME;
#pragma unroll
        for (int c = 0; c < 3; ++c) {
            int p = 4 * s + 64 * c;
            if (p < FRAME) {
                float4 a4 = *(const float4*)(pAg + p);
                float4 b4 = *(const float4*)(pBg + p);
                float4* dst = (float4*)&s_x[wave][g][12 + p];   // 16B aligned
                dst[0] = make_float4(a4.x, b4.x, a4.y, b4.y);
                dst[1] = make_float4(a4.z, b4.z, a4.w, b4.w);
            }
        }
    }
    __builtin_amdgcn_wave_barrier();

    const v2f* X = &s_x[wave][g][12];    // X[p] = {xA[p], xB[p]}, p in [-12, 160]
    const int p0 = s * EPL;

    // Windowed products; b[p]=xw[p], f[p]=xw[p+1]; position 159 zero invariant
    // (X[160] = 0 via tail pad AND win[160] = 0).
    v2f F[EPL], B[EPL];
    {
        v2f pr[EPL + 1];
#pragma unroll
        for (int j = 0; j <= EPL; ++j)
            pr[j] = X[p0 + j] * s_win[p0 + j];
#pragma unroll
        for (int t = 0; t < EPL; ++t) { F[t] = pr[t + 1]; B[t] = pr[t]; }
    }
    if (s == 15) B[EPL - 1] = splat2(0.f);
    v2f dpF = splat2(0.f), dpB = splat2(0.f);
#pragma unroll
    for (int t = 0; t < EPL; ++t) {
        dpF = pkfma(F[t], F[t], dpF);
        dpB = pkfma(B[t], B[t], dpB);
    }
    v2f den = rowsum16v(dpF + dpB);

    v2f a  = (s == 0) ? splat2(1.f) : splat2(0.f);
    v2f ar = (s == 1) ? splat2(1.f) : splat2(0.f);
    v2f cp = splat2(0.f), dsc = splat2(0.f);

#pragma unroll
    for (int i = 0; i < ORDER; ++i) {
        v2f q0 = splat2(0.f), q1 = splat2(0.f);
#pragma unroll
        for (int t = 0; t < EPL; t += 2) {
            q0 = pkfma(F[t],     B[t],     q0);
            q1 = pkfma(F[t + 1], B[t + 1], q1);
        }
        v2f num = rowsum16v(q0 + q1);
        if (i > 0) den = dsc - rowsum16v(cp);
        v2f r;
        r.x = -2.0f * num.x * __builtin_amdgcn_rcpf(den.x);
        r.y = -2.0f * num.y * __builtin_amdgcn_rcpf(den.y);

        // a[:i+2] += r*a[:i+2][::-1]:  a'=a+r*ar ; ar'=(ar+r*a)>>1 lane
        v2f an  = pkfma(r, ar, a);
        v2f arn = pkfma(r, a, ar);
        a = an;
        ar.x = dppf<0x111>(arn.x);       // row_shr:1, lane0 <- 0
        ar.y = dppf<0x111>(arn.y);

        // In-place lattice update (each pk op serves BOTH frames).
#pragma unroll
        for (int t = 0; t < EPL; ++t) {
            v2f fo = F[t];
            F[t] = pkfma(r, B[t], fo);
            B[t] = pkfma(r, fo, B[t]);
        }

        const int pe = 158 - i;          // compile-time (full unroll)
        const int SL = pe / EPL, SS = pe % EPL;
        v2f fe = (s == 0)  ? F[0]  : splat2(0.f);
        v2f be = (s == SL) ? B[SS] : splat2(0.f);
        cp  = pkfma(fe, fe, be * be);
        dsc = pkfma(-(r * r), den, den); // (1-r^2)*den

        // f = f'[1:]  (row_shl:1; lane15 -> 0 keeps invariant)
        v2f up;
        up.x = dppf<0x101>(F[0].x);
        up.y = dppf<0x101>(F[0].y);
#pragma unroll
        for (int t = 0; t < EPL - 1; ++t) F[t] = F[t + 1];
        F[EPL - 1] = up;
        if (s == SL) B[SS] = splat2(0.f);
    }

    // Broadcast packed a[0..12] within the group via same-wave LDS bounce.
    s_a[wave][g][s] = a;
    __builtin_amdgcn_wave_barrier();
    v2f ak[ORDER + 1];
#pragma unroll
    for (int k = 0; k <= ORDER; ++k) ak[k] = s_a[wave][g][k];

    const float alpha = alpha_p[0];
    v2f ac;
    ac.x = alpha * (2.0f * (float)bits[fA] - 1.0f);
    ac.y = alpha * (2.0f * (float)bits[fB] - 1.0f);

    // FIR, store-coalesced mapping: lane s computes positions base..base+3,
    // base = 4s + 64c. Sliding window W[j] = X[base-12+j], j=0..15 (front pad
    // covers history; k-ascending tap order identical to before).
    // y[base+t] = sum_k ak[k]*W[12+t-k]; out = W[12+t] + ac*y.
    // Stores: float4 per frame per chunk -> 256B contiguous per group.
    float* oAf = out + (size_t)fA * FRAME;
    float* oBf = out + (size_t)fB * FRAME;
#pragma unroll
    for (int c = 0; c < 3; ++c) {
        const int base = 4 * s + 64 * c;
        if (base < FRAME) {
            v2f W[16];
#pragma unroll
            for (int j = 0; j < 16; j += 2) {
                // (base-12+j) even for even j -> 16B-aligned b128 read.
                float4 q = *(const float4*)&X[base - 12 + j];
                W[j].x = q.x;     W[j].y = q.y;
                W[j + 1].x = q.z; W[j + 1].y = q.w;
            }
            v2f r4[4];
#pragma unroll
            for (int t = 0; t < 4; ++t) {
                v2f acc = splat2(0.f);
#pragma unroll
                for (int k = 0; k <= ORDER; ++k)
                    acc = pkfma(ak[k], W[12 + t - k], acc);
                r4[t] = pkfma(ac, acc, W[12 + t]);
            }
            *(float4*)(oAf + base) = make_float4(r4[0].x, r4[1].x, r4[2].x, r4[3].x);
            *(float4*)(oBf + base) = make_float4(r4[0].y, r4[1].y, r4[2].y, r4[3].y);
        }
    }
}

extern "C" void kernel_launch(void* const* d_in, const int* in_sizes, int n_in,
                              void* d_out, int out_size, void* d_ws, size_t ws_size,
                              hipStream_t stream) {
    const int*   bits  = (const int*)d_in[0];
    const float* pcm   = (const float*)d_in[1];
    const float* alpha = (const float*)d_in[2];
    float*       out   = (float*)d_out;

    // 61440 frames; 16 per block (2 waves x 4 groups x 2 packed frames).
    dim3 grid(NFRAMES / 16), block(128);
    hipLaunchKernelGGL(ResidualEmbedding_70798240907390_kernel, grid, block, 0, stream,
                       bits, pcm, alpha, out);
}